// Round 4
// baseline (178.520 us; speedup 1.0000x reference)
//
#include <hip/hip_runtime.h>
#include <hip/hip_bf16.h>

#define N_TOK 4096
#define DIM   1024
#define H2V   4096
#define HV    2048
#define NE    8
#define BM    128
#define BN    64                 // output cols per block (W cols staged = 2*BN)
#define BK    64
#define NTHR  256
#define KSTEPS (DIM / BK)        // 16
#define ROW_TILES (N_TOK / BM)   // 32 worst-case row tiles per expert

// d_ws layout
#define WS_COUNTS 0
#define WS_BASE   64             // 9 ints
#define WS_SLOTS  128            // NE*N_TOK u16 = 64 KiB
#define WS_XPERM  66560          // (N_TOK+BM) rows x DIM bf16 = 8.65 MB

typedef __attribute__((ext_vector_type(4))) float  f32x4;
typedef __attribute__((ext_vector_type(8))) short  s16x8;

__device__ __forceinline__ unsigned short f2bf(float f) {
    union { __hip_bfloat16 h; unsigned short u; } v;
    v.h = __float2bfloat16(f);
    return v.u;
}

__global__ void k_init(int* __restrict__ counts) {
    if (threadIdx.x < NE) counts[threadIdx.x] = 0;
}

__global__ void k_scatter(const int* __restrict__ idx, int* __restrict__ counts,
                          unsigned short* __restrict__ slots) {
    int n = blockIdx.x * blockDim.x + threadIdx.x;
    if (n < N_TOK) {
        int e = idx[n];
        int p = atomicAdd(&counts[e], 1);
        slots[e * N_TOK + p] = (unsigned short)n;
    }
}

__global__ void k_base(const int* __restrict__ counts, int* __restrict__ base) {
    if (threadIdx.x == 0) {
        int b = 0;
#pragma unroll
        for (int e = 0; e < NE; ++e) { base[e] = b; b += counts[e]; }
        base[NE] = b;
    }
}

// gather X rows into expert-sorted bf16 X_perm; 4 rows per block
__global__ void k_gather(const float* __restrict__ X, const int* __restrict__ base,
                         const unsigned short* __restrict__ slots,
                         unsigned short* __restrict__ Xp) {
    const int r    = blockIdx.x * 4 + (threadIdx.x >> 6);
    const int lane = threadIdx.x & 63;
    int e = 0;
#pragma unroll
    for (int i = 0; i < NE - 1; ++i) if (r >= base[i + 1]) e = i + 1;
    const int tok = slots[e * N_TOK + (r - base[e])];
    const float* src = X + (size_t)tok * DIM + lane * 16;
    unsigned short* dst = Xp + (size_t)r * DIM + lane * 16;
    f32x4 v0 = *(const f32x4*)(src);
    f32x4 v1 = *(const f32x4*)(src + 4);
    f32x4 v2 = *(const f32x4*)(src + 8);
    f32x4 v3 = *(const f32x4*)(src + 12);
    unsigned short t0[8], t1[8];
#pragma unroll
    for (int i = 0; i < 4; ++i) { t0[i] = f2bf(v0[i]); t0[4 + i] = f2bf(v1[i]); }
#pragma unroll
    for (int i = 0; i < 4; ++i) { t1[i] = f2bf(v2[i]); t1[4 + i] = f2bf(v3[i]); }
    *(s16x8*)(dst)     = *(const s16x8*)t0;
    *(s16x8*)(dst + 8) = *(const s16x8*)t1;
}

__global__ __launch_bounds__(NTHR, 3) void k_gemm(
        const float* __restrict__ W, const int* __restrict__ counts,
        const int* __restrict__ base, const unsigned short* __restrict__ slots,
        const unsigned short* __restrict__ Xp, float* __restrict__ out) {
    const int ct = blockIdx.x;          // 0..31
    const int e  = blockIdx.y >> 5;
    const int rt = blockIdx.y & 31;
    const int cnt = counts[e];
    const int tbase = rt * BM;
    if (tbase >= cnt) return;
    const int row_g0 = base[e] + tbase;     // global X_perm row of tile row 0

    // As[buf]: [row][k] bf16, swizzled slot = q ^ (row&7) (written via pre-swizzled
    // global source + linear global_load_lds). Bs: [col][k] bf16 transposed W,
    // slot = ko ^ (((c>>1)^(c>>4))&7).
    __shared__ unsigned short As[2][BM * BK];   // 2 x 16 KiB
    __shared__ unsigned short Bs[2 * BN * BK];  // 16 KiB

    const int t    = threadIdx.x;
    const int lane = t & 63;
    const int wid  = t >> 6;
    const int wm   = wid >> 1;
    const int wn   = wid & 1;
    const int l16  = lane & 15;
    const int g16  = lane >> 4;

    // ---- A staging via global_load_lds: 4 instrs/thread, pre-swizzled source ----
    const unsigned short* aptr[4];
#pragma unroll
    for (int j = 0; j < 4; ++j) {
        int i  = wid * 4 + j;
        int rl = i * 8 + (lane >> 3);
        int qs = (lane & 7) ^ ((lane >> 3) & 7);
        aptr[j] = Xp + (size_t)(row_g0 + rl) * DIM + qs * 8;
    }
    // ---- B staging: thread loads 4 consecutive W cols x 8 k as 8 dwordx4 ----
    const int c0 = (t & 31) * 4;        // local col 0..124
    const int ko = t >> 5;              // k-octet 0..7
    const int gc = ct * BN + (c0 & 63) + (c0 >> 6) * HV;
    const float* bptr = W + (size_t)e * DIM * H2V + (size_t)(ko * 8) * H2V + gc;

    f32x4 acc[2][4][2];
    const f32x4 zero = {0.f, 0.f, 0.f, 0.f};
#pragma unroll
    for (int g = 0; g < 2; ++g)
#pragma unroll
        for (int m = 0; m < 4; ++m)
#pragma unroll
            for (int n = 0; n < 2; ++n) acc[g][m][n] = zero;

    f32x4 bv0[8], bv1[8];               // named 2-deep B pipeline (rule #20)

    auto issueA = [&](int ks, int buf) {
#pragma unroll
        for (int j = 0; j < 4; ++j) {
            const unsigned short* g = aptr[j] + ks * BK;
            unsigned short* l = (unsigned short*)&As[buf][(wid * 4 + j) * 512];
            __builtin_amdgcn_global_load_lds(
                (const __attribute__((address_space(1))) unsigned int*)(const void*)g,
                (__attribute__((address_space(3))) unsigned int*)(void*)l, 16, 0, 0);
        }
    };
    auto loadB = [&](int ks, f32x4 (&bv)[8]) {
#pragma unroll
        for (int i = 0; i < 8; ++i)
            bv[i] = *(const f32x4*)(bptr + (size_t)(ks * BK + i) * H2V);
    };
    auto storeB = [&](const f32x4 (&bv)[8]) {
#pragma unroll
        for (int j = 0; j < 4; ++j) {
            int c = c0 + j;
            int key = ((c >> 1) ^ (c >> 4)) & 7;
            unsigned short tmp[8];
#pragma unroll
            for (int i = 0; i < 8; ++i) tmp[i] = f2bf(bv[i][j]);
            *(s16x8*)&Bs[c * 64 + ((ko ^ key) * 8)] = *(const s16x8*)tmp;
        }
    };
    auto mfmaPhase = [&](int cur) {
#pragma unroll
        for (int kk = 0; kk < 2; ++kk) {
            const int gran = kk * 4 + g16;
            s16x8 af[4], bfr[2][2];
#pragma unroll
            for (int m = 0; m < 4; ++m) {
                int row = wm * 64 + m * 16 + l16;
                af[m] = *(const s16x8*)&As[cur][row * 64 + ((gran ^ (row & 7)) * 8)];
            }
#pragma unroll
            for (int g = 0; g < 2; ++g)
#pragma unroll
                for (int n = 0; n < 2; ++n) {
                    int c = g * BN + wn * 32 + n * 16 + l16;
                    int key = ((c >> 1) ^ (c >> 4)) & 7;
                    bfr[g][n] = *(const s16x8*)&Bs[c * 64 + ((gran ^ key) * 8)];
                }
#pragma unroll
            for (int g = 0; g < 2; ++g)
#pragma unroll
                for (int m = 0; m < 4; ++m)
#pragma unroll
                    for (int n = 0; n < 2; ++n)
                        acc[g][m][n] = __builtin_amdgcn_mfma_f32_16x16x32_bf16(
                            af[m], bfr[g][n], acc[g][m][n], 0, 0, 0);
        }
    };

    // body(ks): needs A(ks) in As[ks&1], B(ks) in its parity reg set.
    // Issue-order invariant at top of iter ks (steady state):
    //   ... A(ks)[4] < B(ks+1)[8] < A(ks+1 — not yet) ; outstanding youngest 8 = B(ks+1).
    // After issuing inside this iter: A(ks+1)[4], B(ks+2)[8].
    // vmcnt(8) at top => everything older than the 8 youngest (B(ks+2) next iter) done.
    auto body = [&](int ks, f32x4 (&bv)[8]) {
        const int cur = ks & 1;
        if (ks + 1 < KSTEPS) {
            asm volatile("s_waitcnt vmcnt(8)" ::: "memory");
        } else {
            asm volatile("s_waitcnt vmcnt(0)" ::: "memory");
        }
        __builtin_amdgcn_sched_barrier(0);
        __builtin_amdgcn_s_barrier();        // As[cur^1] free (prev MFMA done), A(ks)/B(ks) ready
        storeB(bv);                          // consume B(ks)
        if (ks + 1 < KSTEPS) issueA(ks + 1, cur ^ 1);
        if (ks + 2 < KSTEPS) loadB(ks + 2, bv);   // refill same parity set, 2-iter window
        asm volatile("s_waitcnt lgkmcnt(0)" ::: "memory");
        __builtin_amdgcn_sched_barrier(0);
        __builtin_amdgcn_s_barrier();        // Bs visible; vmcnt NOT drained here
        mfmaPhase(cur);
    };

    // prologue: B(0), A(0), B(1) in flight
    loadB(0, bv0);
    issueA(0, 0);
    loadB(1, bv1);

#pragma unroll 1
    for (int ks = 0; ks < KSTEPS; ks += 2) {
        body(ks, bv0);
        body(ks + 1, bv1);
    }

    // epilogue: silu(gate) * up, scatter rows to token ids
    const unsigned short* ids = slots + e * N_TOK;
#pragma unroll
    for (int m = 0; m < 4; ++m) {
#pragma unroll
        for (int r = 0; r < 4; ++r) {
            int rowt = wm * 64 + m * 16 + g16 * 4 + r;
            int slot = tbase + rowt;
            if (slot < cnt) {
                int tok = ids[slot];
#pragma unroll
                for (int n = 0; n < 2; ++n) {
                    int col = ct * BN + wn * 32 + n * 16 + l16;
                    float a = acc[0][m][n][r];
                    float b = acc[1][m][n][r];
                    float sg = a / (1.0f + __expf(-a));
                    out[(size_t)tok * HV + col] = sg * b;
                }
            }
        }
    }
}

extern "C" void kernel_launch(void* const* d_in, const int* in_sizes, int n_in,
                              void* d_out, int out_size, void* d_ws, size_t ws_size,
                              hipStream_t stream) {
    const float* X  = (const float*)d_in[0];
    const float* W  = (const float*)d_in[1];
    const int* idx  = (const int*)d_in[2];
    float* out      = (float*)d_out;

    int* counts = (int*)((char*)d_ws + WS_COUNTS);
    int* base   = (int*)((char*)d_ws + WS_BASE);
    unsigned short* slots = (unsigned short*)((char*)d_ws + WS_SLOTS);
    unsigned short* Xp    = (unsigned short*)((char*)d_ws + WS_XPERM);

    k_init<<<1, 64, 0, stream>>>(counts);
    k_scatter<<<N_TOK / 256, 256, 0, stream>>>(idx, counts, slots);
    k_base<<<1, 64, 0, stream>>>(counts, base);
    k_gather<<<N_TOK / 4, 256, 0, stream>>>(X, base, slots, Xp);
    dim3 grid(HV / BN, NE * ROW_TILES);
    k_gemm<<<grid, NTHR, 0, stream>>>(W, counts, base, slots, Xp, out);
}

// Round 5
// 106.208 us; speedup vs baseline: 1.6808x; 1.6808x over previous
//
#include <hip/hip_runtime.h>
#include <hip/hip_bf16.h>

#define N_TOK 4096
#define DIM   1024
#define H2V   4096
#define HV    2048
#define NE    8
#define BM    128
#define BN    64                 // output cols per block (W cols staged = 2*BN)
#define BK    64
#define NTHR  256
#define KSTEPS (DIM / BK)        // 16
#define ROW_TILES (N_TOK / BM)   // 32 worst-case row tiles per expert

// d_ws layout
#define WS_COUNTS 0
#define WS_BASE   64             // 9 ints
#define WS_SLOTS  128            // NE*N_TOK u16 = 64 KiB
#define WS_XPERM  66560          // (N_TOK+BM) rows x DIM bf16 = 8.65 MB

typedef __attribute__((ext_vector_type(4))) float  f32x4;
typedef __attribute__((ext_vector_type(8))) short  s16x8;

__device__ __forceinline__ unsigned short f2bf(float f) {
    union { __hip_bfloat16 h; unsigned short u; } v;
    v.h = __float2bfloat16(f);
    return v.u;
}

__global__ void k_init(int* __restrict__ counts) {
    if (threadIdx.x < NE) counts[threadIdx.x] = 0;
}

__global__ void k_scatter(const int* __restrict__ idx, int* __restrict__ counts,
                          unsigned short* __restrict__ slots) {
    int n = blockIdx.x * blockDim.x + threadIdx.x;
    if (n < N_TOK) {
        int e = idx[n];
        int p = atomicAdd(&counts[e], 1);
        slots[e * N_TOK + p] = (unsigned short)n;
    }
}

__global__ void k_base(const int* __restrict__ counts, int* __restrict__ base) {
    if (threadIdx.x == 0) {
        int b = 0;
#pragma unroll
        for (int e = 0; e < NE; ++e) { base[e] = b; b += counts[e]; }
        base[NE] = b;
    }
}

// gather X rows into expert-sorted bf16 X_perm; 4 rows per block
__global__ void k_gather(const float* __restrict__ X, const int* __restrict__ base,
                         const unsigned short* __restrict__ slots,
                         unsigned short* __restrict__ Xp) {
    const int r    = blockIdx.x * 4 + (threadIdx.x >> 6);
    const int lane = threadIdx.x & 63;
    int e = 0;
#pragma unroll
    for (int i = 0; i < NE - 1; ++i) if (r >= base[i + 1]) e = i + 1;
    const int tok = slots[e * N_TOK + (r - base[e])];
    const float* src = X + (size_t)tok * DIM + lane * 16;
    unsigned short* dst = Xp + (size_t)r * DIM + lane * 16;
    f32x4 v0 = *(const f32x4*)(src);
    f32x4 v1 = *(const f32x4*)(src + 4);
    f32x4 v2 = *(const f32x4*)(src + 8);
    f32x4 v3 = *(const f32x4*)(src + 12);
    unsigned short t0[8], t1[8];
#pragma unroll
    for (int i = 0; i < 4; ++i) { t0[i] = f2bf(v0[i]); t0[4 + i] = f2bf(v1[i]); }
#pragma unroll
    for (int i = 0; i < 4; ++i) { t1[i] = f2bf(v2[i]); t1[4 + i] = f2bf(v3[i]); }
    *(s16x8*)(dst)     = *(const s16x8*)t0;
    *(s16x8*)(dst + 8) = *(const s16x8*)t1;
}

__global__ __launch_bounds__(NTHR, 2) void k_gemm(
        const float* __restrict__ W, const int* __restrict__ counts,
        const int* __restrict__ base, const unsigned short* __restrict__ slots,
        const unsigned short* __restrict__ Xp, float* __restrict__ out) {
    const int ct = blockIdx.x;          // 0..31
    const int e  = blockIdx.y >> 5;
    const int rt = blockIdx.y & 31;
    const int cnt = counts[e];
    const int tbase = rt * BM;
    if (tbase >= cnt) return;
    const int row_g0 = base[e] + tbase;     // global X_perm row of tile row 0

    // As[buf]: [row][k] bf16, swizzled slot = q ^ (row&7) (pre-swizzled global
    // source + linear global_load_lds). Bs[buf]: [col][k] bf16 transposed W,
    // slot = ko ^ (((c>>1)^(c>>4))&7). Both double-buffered: 4 x 16 KiB.
    __shared__ unsigned short As[2][BM * BK];
    __shared__ unsigned short Bs[2][2 * BN * BK];

    const int t    = threadIdx.x;
    const int lane = t & 63;
    const int wid  = t >> 6;
    const int wm   = wid >> 1;
    const int wn   = wid & 1;
    const int l16  = lane & 15;
    const int g16  = lane >> 4;

    // ---- A staging via global_load_lds: 4 instrs/thread, pre-swizzled source ----
    const unsigned short* aptr[4];
#pragma unroll
    for (int j = 0; j < 4; ++j) {
        int i  = wid * 4 + j;
        int rl = i * 8 + (lane >> 3);
        int qs = (lane & 7) ^ ((lane >> 3) & 7);
        aptr[j] = Xp + (size_t)(row_g0 + rl) * DIM + qs * 8;
    }
    // ---- B staging: thread loads 4 consecutive W cols x 8 k as 8 dwordx4 ----
    const int c0 = (t & 31) * 4;        // local col 0..124
    const int ko = t >> 5;              // k-octet 0..7
    const int gc = ct * BN + (c0 & 63) + (c0 >> 6) * HV;
    const float* bptr = W + (size_t)e * DIM * H2V + (size_t)(ko * 8) * H2V + gc;

    f32x4 acc[2][4][2];
    const f32x4 zero = {0.f, 0.f, 0.f, 0.f};
#pragma unroll
    for (int g = 0; g < 2; ++g)
#pragma unroll
        for (int m = 0; m < 4; ++m)
#pragma unroll
            for (int n = 0; n < 2; ++n) acc[g][m][n] = zero;

    f32x4 bv[8];                        // SINGLE register set (no spill)

    auto issueA = [&](int ks, int buf) {
#pragma unroll
        for (int j = 0; j < 4; ++j) {
            const unsigned short* g = aptr[j] + ks * BK;
            unsigned short* l = (unsigned short*)&As[buf][(wid * 4 + j) * 512];
            __builtin_amdgcn_global_load_lds(
                (const __attribute__((address_space(1))) unsigned int*)(const void*)g,
                (__attribute__((address_space(3))) unsigned int*)(void*)l, 16, 0, 0);
        }
    };
    auto loadB = [&](int ks) {
#pragma unroll
        for (int i = 0; i < 8; ++i)
            bv[i] = *(const f32x4*)(bptr + (size_t)(ks * BK + i) * H2V);
    };
    auto storeB = [&](int buf) {
#pragma unroll
        for (int j = 0; j < 4; ++j) {
            int c = c0 + j;
            int key = ((c >> 1) ^ (c >> 4)) & 7;
            unsigned short tmp[8];
#pragma unroll
            for (int i = 0; i < 8; ++i) tmp[i] = f2bf(bv[i][j]);
            *(s16x8*)&Bs[buf][c * 64 + ((ko ^ key) * 8)] = *(const s16x8*)tmp;
        }
    };
    auto mfmaPhase = [&](int cur) {
        __builtin_amdgcn_s_setprio(1);
#pragma unroll
        for (int kk = 0; kk < 2; ++kk) {
            const int gran = kk * 4 + g16;
            s16x8 af[4], bfr[2][2];
#pragma unroll
            for (int m = 0; m < 4; ++m) {
                int row = wm * 64 + m * 16 + l16;
                af[m] = *(const s16x8*)&As[cur][row * 64 + ((gran ^ (row & 7)) * 8)];
            }
#pragma unroll
            for (int g = 0; g < 2; ++g)
#pragma unroll
                for (int n = 0; n < 2; ++n) {
                    int c = g * BN + wn * 32 + n * 16 + l16;
                    int key = ((c >> 1) ^ (c >> 4)) & 7;
                    bfr[g][n] = *(const s16x8*)&Bs[cur][c * 64 + ((gran ^ key) * 8)];
                }
#pragma unroll
            for (int g = 0; g < 2; ++g)
#pragma unroll
                for (int m = 0; m < 4; ++m)
#pragma unroll
                    for (int n = 0; n < 2; ++n)
                        acc[g][m][n] = __builtin_amdgcn_mfma_f32_16x16x32_bf16(
                            af[m], bfr[g][n], acc[g][m][n], 0, 0, 0);
        }
        __builtin_amdgcn_s_setprio(0);
    };

    // ---- prologue: B(0)+A(0) in flight, then stage Bs[0], start B(1) ----
    loadB(0);
    issueA(0, 0);
    asm volatile("s_waitcnt vmcnt(0)" ::: "memory");
    __builtin_amdgcn_sched_barrier(0);
    storeB(0);
    loadB(1);                           // 8 loads in flight across iter 0
    asm volatile("s_waitcnt lgkmcnt(0)" ::: "memory");
    __builtin_amdgcn_sched_barrier(0);

    // ---- main loop ----
    // top-of-iter ks outstanding (per wave): A(ks)[4] (older) + B(ks+1)[8] (younger)
#pragma unroll 2
    for (int ks = 0; ks < KSTEPS; ++ks) {
        const int cur = ks & 1;
        if (ks == KSTEPS - 1) {
            asm volatile("s_waitcnt vmcnt(0)" ::: "memory");
        } else {
            asm volatile("s_waitcnt vmcnt(8)" ::: "memory");   // A(ks) done
        }
        __builtin_amdgcn_sched_barrier(0);
        __builtin_amdgcn_s_barrier();       // As[cur],Bs[cur] valid; old bufs free
        if (ks + 1 < KSTEPS) issueA(ks + 1, cur ^ 1);
        mfmaPhase(cur);                     // B(ks+1) loads land under this
        if (ks + 1 < KSTEPS) {
            asm volatile("s_waitcnt vmcnt(4)" ::: "memory");   // B(ks+1) done, A(ks+1) in flight
            __builtin_amdgcn_sched_barrier(0);
            storeB(cur ^ 1);
            if (ks + 2 < KSTEPS) loadB(ks + 2);
            asm volatile("s_waitcnt lgkmcnt(0)" ::: "memory"); // own ds_writes done pre-barrier
            __builtin_amdgcn_sched_barrier(0);
        }
    }

    // epilogue: silu(gate) * up, scatter rows to token ids
    const unsigned short* ids = slots + e * N_TOK;
#pragma unroll
    for (int m = 0; m < 4; ++m) {
#pragma unroll
        for (int r = 0; r < 4; ++r) {
            int rowt = wm * 64 + m * 16 + g16 * 4 + r;
            int slot = tbase + rowt;
            if (slot < cnt) {
                int tok = ids[slot];
#pragma unroll
                for (int n = 0; n < 2; ++n) {
                    int col = ct * BN + wn * 32 + n * 16 + l16;
                    float a = acc[0][m][n][r];
                    float b = acc[1][m][n][r];
                    float sg = a / (1.0f + __expf(-a));
                    out[(size_t)tok * HV + col] = sg * b;
                }
            }
        }
    }
}

extern "C" void kernel_launch(void* const* d_in, const int* in_sizes, int n_in,
                              void* d_out, int out_size, void* d_ws, size_t ws_size,
                              hipStream_t stream) {
    const float* X  = (const float*)d_in[0];
    const float* W  = (const float*)d_in[1];
    const int* idx  = (const int*)d_in[2];
    float* out      = (float*)d_out;

    int* counts = (int*)((char*)d_ws + WS_COUNTS);
    int* base   = (int*)((char*)d_ws + WS_BASE);
    unsigned short* slots = (unsigned short*)((char*)d_ws + WS_SLOTS);
    unsigned short* Xp    = (unsigned short*)((char*)d_ws + WS_XPERM);

    k_init<<<1, 64, 0, stream>>>(counts);
    k_scatter<<<N_TOK / 256, 256, 0, stream>>>(idx, counts, slots);
    k_base<<<1, 64, 0, stream>>>(counts, base);
    k_gather<<<N_TOK / 4, 256, 0, stream>>>(X, base, slots, Xp);
    dim3 grid(HV / BN, NE * ROW_TILES);
    k_gemm<<<grid, NTHR, 0, stream>>>(W, counts, base, slots, Xp, out);
}